// Round 2
// baseline (639.577 us; speedup 1.0000x reference)
//
#include <hip/hip_runtime.h>

// TurboFlashAttention: causal attention B=2,H=16,S=2048,D=64 fp32, plus a
// 512MB all-zeros attn_weights placeholder (dominates runtime: ~85us HBM floor).
// Strategy: fused kernel — flash attention (bf16 MFMA 16x16x32) + per-block
// zero-fill of the placeholder region, so zero stores overlap compute.

typedef __bf16 bf16x8 __attribute__((ext_vector_type(8)));
typedef float f32x4 __attribute__((ext_vector_type(4)));

#define LOG2E 1.44269504088896340736f

__device__ __forceinline__ unsigned short f2bf(float f) {
  unsigned int u = __float_as_uint(f);
  u += 0x7fffu + ((u >> 16) & 1u);   // RNE; inputs are finite normals
  return (unsigned short)(u >> 16);
}

union U8 { unsigned short u[8]; bf16x8 v; };

constexpr int Sdim = 2048, Ddim = 64, BHn = 32;
constexpr int BM = 64, BN = 64;
constexpr int QTiles = Sdim / BM;            // 32
constexpr int LDK = 72;                      // padded LDS stride (2-way conflicts only)
constexpr int OUT0 = BHn * Sdim * Ddim;      // 4,194,304 floats (output region)
constexpr int ZF4_PER_BLOCK = 32768;         // 134217728 floats / 4 / 1024 blocks

__global__ __launch_bounds__(256, 2)
void flash_causal_kernel(const float* __restrict__ Q, const float* __restrict__ K,
                         const float* __restrict__ V, float* __restrict__ out) {
  __shared__ unsigned short Klds[BN * LDK];      // [kn][d]  row-major
  __shared__ unsigned short Vlds[Ddim * LDK];    // [d][kn]  transposed
  __shared__ unsigned short Plds[4][16 * LDK];   // per-wave [qm][kn]

  const int tid  = threadIdx.x;
  const int wave = tid >> 6;
  const int lane = tid & 63;
  const int quad = lane >> 4;
  const int l15  = lane & 15;

  const int bh = blockIdx.x & (BHn - 1);
  const int qt = (QTiles - 1) - (int)(blockIdx.x >> 5);  // heavy tiles first

  const int base  = bh * Sdim * Ddim;
  const int qrow0 = qt * BM + wave * 16;

  // ---- Q fragments in registers (A-layout: A[m=l15][k=quad*8+j]), scale folded.
  bf16x8 aq[2];
  {
    const float* qp = Q + base + (qrow0 + l15) * Ddim + quad * 8;
    #pragma unroll
    for (int s = 0; s < 2; ++s) {
      float4 a = *(const float4*)(qp + 32 * s);
      float4 b = *(const float4*)(qp + 32 * s + 4);
      U8 u;
      u.u[0] = f2bf(a.x * 0.125f); u.u[1] = f2bf(a.y * 0.125f);
      u.u[2] = f2bf(a.z * 0.125f); u.u[3] = f2bf(a.w * 0.125f);
      u.u[4] = f2bf(b.x * 0.125f); u.u[5] = f2bf(b.y * 0.125f);
      u.u[6] = f2bf(b.z * 0.125f); u.u[7] = f2bf(b.w * 0.125f);
      aq[s] = u.v;
    }
  }

  f32x4 ot[4];
  #pragma unroll
  for (int t = 0; t < 4; ++t) ot[t] = (f32x4){0.f, 0.f, 0.f, 0.f};
  float mrun[4], lrun[4];
  #pragma unroll
  for (int r = 0; r < 4; ++r) { mrun[r] = -__builtin_inff(); lrun[r] = 0.f; }

  const float4* kg4 = (const float4*)(K + base);
  const float4* vg4 = (const float4*)(V + base);

  for (int j = 0; j <= qt; ++j) {
    // ---- stage K (row-major bf16) and V (transposed bf16) into LDS
    const float4* kp = kg4 + j * 1024;
    const float4* vp = vg4 + j * 1024;
    #pragma unroll
    for (int rr = 0; rr < 4; ++rr) {
      int lin = rr * 256 + tid;          // 0..1023
      int row = lin >> 4;                // kn row 0..63
      int c4  = (lin & 15) << 2;         // d col 0,4,..60
      float4 fk = kp[lin];
      float4 fv = vp[lin];
      unsigned int k01 = (unsigned int)f2bf(fk.x) | ((unsigned int)f2bf(fk.y) << 16);
      unsigned int k23 = (unsigned int)f2bf(fk.z) | ((unsigned int)f2bf(fk.w) << 16);
      uint2 t2; t2.x = k01; t2.y = k23;
      *(uint2*)&Klds[row * LDK + c4] = t2;
      Vlds[(c4 + 0) * LDK + row] = f2bf(fv.x);
      Vlds[(c4 + 1) * LDK + row] = f2bf(fv.y);
      Vlds[(c4 + 2) * LDK + row] = f2bf(fv.z);
      Vlds[(c4 + 3) * LDK + row] = f2bf(fv.w);
    }
    __syncthreads();

    // ---- S = Q * K^T  (C-layout: S[qm=quad*4+r][kn=16t+l15])
    f32x4 sc[4];
    #pragma unroll
    for (int t = 0; t < 4; ++t) sc[t] = (f32x4){0.f, 0.f, 0.f, 0.f};
    #pragma unroll
    for (int s = 0; s < 2; ++s) {
      #pragma unroll
      for (int t = 0; t < 4; ++t) {
        bf16x8 bk = *(const bf16x8*)&Klds[(16 * t + l15) * LDK + 32 * s + quad * 8];
        sc[t] = __builtin_amdgcn_mfma_f32_16x16x32_bf16(aq[s], bk, sc[t], 0, 0, 0);
      }
    }

    // ---- causal mask (diagonal tile only)
    if (j == qt) {
      #pragma unroll
      for (int t = 0; t < 4; ++t)
        #pragma unroll
        for (int r = 0; r < 4; ++r)
          if (16 * t + l15 > wave * 16 + quad * 4 + r) sc[t][r] = -__builtin_inff();
    }

    // ---- online softmax (rows live on (quad, r); reduce across l15)
    float mx[4];
    #pragma unroll
    for (int r = 0; r < 4; ++r) {
      float m0 = fmaxf(fmaxf(sc[0][r], sc[1][r]), fmaxf(sc[2][r], sc[3][r]));
      #pragma unroll
      for (int off = 1; off < 16; off <<= 1) m0 = fmaxf(m0, __shfl_xor(m0, off));
      mx[r] = m0;
    }
    float alpha[4], msc[4];
    #pragma unroll
    for (int r = 0; r < 4; ++r) {
      float mn = fmaxf(mrun[r], mx[r]);
      alpha[r] = __builtin_amdgcn_exp2f((mrun[r] - mn) * LOG2E);
      msc[r]   = mn * LOG2E;
      mrun[r]  = mn;
    }
    float rs[4] = {0.f, 0.f, 0.f, 0.f};
    #pragma unroll
    for (int t = 0; t < 4; ++t)
      #pragma unroll
      for (int r = 0; r < 4; ++r) {
        float p = __builtin_amdgcn_exp2f(fmaf(sc[t][r], LOG2E, -msc[r]));
        sc[t][r] = p;
        rs[r] += p;
      }
    #pragma unroll
    for (int r = 0; r < 4; ++r) {
      #pragma unroll
      for (int off = 1; off < 16; off <<= 1) rs[r] += __shfl_xor(rs[r], off);
      lrun[r] = lrun[r] * alpha[r] + rs[r];
    }
    #pragma unroll
    for (int t = 0; t < 4; ++t)
      #pragma unroll
      for (int r = 0; r < 4; ++r) ot[t][r] *= alpha[r];

    // ---- P: C-layout -> A-layout via per-wave LDS round-trip
    #pragma unroll
    for (int t = 0; t < 4; ++t)
      #pragma unroll
      for (int r = 0; r < 4; ++r)
        Plds[wave][(quad * 4 + r) * LDK + 16 * t + l15] = f2bf(sc[t][r]);

    // ---- O += P * V  (B-frags from transposed V in LDS)
    #pragma unroll
    for (int s = 0; s < 2; ++s) {
      bf16x8 ap = *(const bf16x8*)&Plds[wave][l15 * LDK + 32 * s + quad * 8];
      #pragma unroll
      for (int t = 0; t < 4; ++t) {
        bf16x8 bv = *(const bf16x8*)&Vlds[(16 * t + l15) * LDK + 32 * s + quad * 8];
        ot[t] = __builtin_amdgcn_mfma_f32_16x16x32_bf16(ap, bv, ot[t], 0, 0, 0);
      }
    }
    __syncthreads();
  }

  // ---- epilogue: normalize and store output region 0
  #pragma unroll
  for (int r = 0; r < 4; ++r) {
    float inv = 1.0f / lrun[r];
    float* orow = out + base + (qrow0 + quad * 4 + r) * Ddim + l15;
    #pragma unroll
    for (int t = 0; t < 4; ++t) orow[16 * t] = ot[t][r] * inv;
  }

  // ---- zero-fill this block's slice of the attn_weights placeholder.
  // Done after the flash loop: light blocks (small qt) finish compute early and
  // stream zeros while heavy blocks are still in MFMA — overlap, not serialize.
  {
    f32x4 z4 = (f32x4){0.f, 0.f, 0.f, 0.f};
    f32x4* zp = (f32x4*)(out + OUT0) + (size_t)blockIdx.x * ZF4_PER_BLOCK + tid;
    #pragma unroll 8
    for (int i = 0; i < ZF4_PER_BLOCK / 256; ++i)
      __builtin_nontemporal_store(z4, zp + i * 256);
  }
}

extern "C" void kernel_launch(void* const* d_in, const int* in_sizes, int n_in,
                              void* d_out, int out_size, void* d_ws, size_t ws_size,
                              hipStream_t stream) {
  const float* q = (const float*)d_in[0];
  const float* k = (const float*)d_in[1];
  const float* v = (const float*)d_in[2];
  float* out = (float*)d_out;
  dim3 grid(BHn * QTiles);   // 1024 blocks: 32 bh * 32 q-tiles, heavy tiles first
  flash_causal_kernel<<<grid, dim3(256), 0, stream>>>(q, k, v, out);
}

// Round 3
// 621.083 us; speedup vs baseline: 1.0298x; 1.0298x over previous
//
#include <hip/hip_runtime.h>

// TurboFlashAttention: causal attention B=2,H=16,S=2048,D=64 fp32, plus a
// 512MB all-zeros attn_weights placeholder.
// R2: S^T formulation (A=K, B=Q) -> per-lane softmax rows, packed P round-trip,
// float4 epilogue; register prefetch of next K/V tile; inverse-balanced zero-fill.

typedef __bf16 bf16x8 __attribute__((ext_vector_type(8)));
typedef float f32x4 __attribute__((ext_vector_type(4)));

#define LOG2E 1.44269504088896340736f

__device__ __forceinline__ unsigned short f2bf(float f) {
  unsigned int u = __float_as_uint(f);
  u += 0x7fffu + ((u >> 16) & 1u);   // RNE; finite values only reach here
  return (unsigned short)(u >> 16);
}

union U8 { unsigned short u[8]; bf16x8 v; };

constexpr int Sdim = 2048, Ddim = 64, BHn = 32;
constexpr int QTiles = Sdim / 64;            // 32
constexpr int LDK = 72;                      // LDS leading-dim pad (shorts)
constexpr int OUT0 = BHn * Sdim * Ddim;      // output region floats (16.8MB)

__global__ __launch_bounds__(256, 2)
void flash_causal_kernel(const float* __restrict__ Q, const float* __restrict__ K,
                         const float* __restrict__ V, float* __restrict__ out) {
  __shared__ unsigned short Klds[64 * LDK];      // K tile [kn][d] row-major bf16
  __shared__ unsigned short Vlds[Ddim * LDK];    // V tile [d][kn] transposed bf16
  __shared__ unsigned short Plds[4][16 * LDK];   // per-wave P [qm][kn]

  const int tid  = threadIdx.x;
  const int wave = tid >> 6;
  const int lane = tid & 63;
  const int quad = lane >> 4;
  const int l15  = lane & 15;

  const int bh = blockIdx.x & (BHn - 1);
  const int g  = (int)(blockIdx.x >> 5);           // 0..31
  const int qt = (QTiles - 1) - g;                 // heavy q-tiles dispatched first

  const int base  = bh * Sdim * Ddim;
  const int qrow0 = qt * 64 + wave * 16;

  // ---- Q fragment (B-operand: lane n=l15=qm, k=quad*8+j), 1/sqrt(64) folded.
  bf16x8 aq[2];
  {
    const float* qp = Q + base + (qrow0 + l15) * Ddim + quad * 8;
    #pragma unroll
    for (int s = 0; s < 2; ++s) {
      float4 a = *(const float4*)(qp + 32 * s);
      float4 b = *(const float4*)(qp + 32 * s + 4);
      U8 u;
      u.u[0] = f2bf(a.x * 0.125f); u.u[1] = f2bf(a.y * 0.125f);
      u.u[2] = f2bf(a.z * 0.125f); u.u[3] = f2bf(a.w * 0.125f);
      u.u[4] = f2bf(b.x * 0.125f); u.u[5] = f2bf(b.y * 0.125f);
      u.u[6] = f2bf(b.z * 0.125f); u.u[7] = f2bf(b.w * 0.125f);
      aq[s] = u.v;
    }
  }

  f32x4 ot[4];                                  // O^T: rows d=16t+4q+r, col qm=l15
  #pragma unroll
  for (int t = 0; t < 4; ++t) ot[t] = (f32x4){0.f, 0.f, 0.f, 0.f};
  float mrun = -__builtin_inff(), lrun = 0.f;   // per-lane (row qm=l15)

  const float4* kg4 = (const float4*)(K + base);
  const float4* vg4 = (const float4*)(V + base);

  // ---- prefetch tile 0 into registers
  float4 kf[4], vf[4];
  #pragma unroll
  for (int i = 0; i < 4; ++i) {
    kf[i] = kg4[i * 256 + tid];
    vf[i] = vg4[i * 256 + tid];
  }

  for (int j = 0; j <= qt; ++j) {
    __syncthreads();                 // previous tile's LDS consumers done
    // ---- regs -> LDS (K row-major, V transposed)
    #pragma unroll
    for (int i = 0; i < 4; ++i) {
      int lin = i * 256 + tid;
      int row = lin >> 4;            // kn 0..63
      int c4  = (lin & 15) << 2;     // d 0,4,..,60
      unsigned int k01 = (unsigned int)f2bf(kf[i].x) | ((unsigned int)f2bf(kf[i].y) << 16);
      unsigned int k23 = (unsigned int)f2bf(kf[i].z) | ((unsigned int)f2bf(kf[i].w) << 16);
      uint2 t2; t2.x = k01; t2.y = k23;
      *(uint2*)&Klds[row * LDK + c4] = t2;
      Vlds[(c4 + 0) * LDK + row] = f2bf(vf[i].x);
      Vlds[(c4 + 1) * LDK + row] = f2bf(vf[i].y);
      Vlds[(c4 + 2) * LDK + row] = f2bf(vf[i].z);
      Vlds[(c4 + 3) * LDK + row] = f2bf(vf[i].w);
    }
    __syncthreads();

    // ---- issue next tile's loads (consumed at next loop-top; hides latency)
    if (j < qt) {
      const float4* kp = kg4 + (j + 1) * 1024;
      const float4* vp = vg4 + (j + 1) * 1024;
      #pragma unroll
      for (int i = 0; i < 4; ++i) {
        kf[i] = kp[i * 256 + tid];
        vf[i] = vp[i * 256 + tid];
      }
    }

    // ---- S^T = K * Q^T  (C-layout: S^T[kn=16t+4q+r][qm=l15])
    f32x4 sc[4];
    #pragma unroll
    for (int t = 0; t < 4; ++t) sc[t] = (f32x4){0.f, 0.f, 0.f, 0.f};
    #pragma unroll
    for (int s = 0; s < 2; ++s) {
      #pragma unroll
      for (int t = 0; t < 4; ++t) {
        bf16x8 ka = *(const bf16x8*)&Klds[(16 * t + l15) * LDK + 32 * s + quad * 8];
        sc[t] = __builtin_amdgcn_mfma_f32_16x16x32_bf16(ka, aq[s], sc[t], 0, 0, 0);
      }
    }

    // ---- causal mask (diagonal tile): kn_local > wave*16 + qm_local
    if (j == qt) {
      const int qml = wave * 16 + l15;
      #pragma unroll
      for (int t = 0; t < 4; ++t)
        #pragma unroll
        for (int r = 0; r < 4; ++r)
          if (16 * t + 4 * quad + r > qml) sc[t][r] = -__builtin_inff();
    }

    // ---- online softmax: row qm=l15 is per-lane (16 regs) + 2 cross-quad shfls
    float mx = sc[0][0];
    #pragma unroll
    for (int t = 0; t < 4; ++t)
      #pragma unroll
      for (int r = 0; r < 4; ++r) mx = fmaxf(mx, sc[t][r]);
    mx = fmaxf(mx, __shfl_xor(mx, 16));
    mx = fmaxf(mx, __shfl_xor(mx, 32));
    float mn    = fmaxf(mrun, mx);
    float alpha = __builtin_amdgcn_exp2f((mrun - mn) * LOG2E);
    float msc   = mn * LOG2E;
    mrun = mn;
    float rs = 0.f;
    #pragma unroll
    for (int t = 0; t < 4; ++t)
      #pragma unroll
      for (int r = 0; r < 4; ++r) {
        float p = __builtin_amdgcn_exp2f(fmaf(sc[t][r], LOG2E, -msc));
        sc[t][r] = p;
        rs += p;
      }
    rs += __shfl_xor(rs, 16);
    rs += __shfl_xor(rs, 32);
    lrun = lrun * alpha + rs;
    #pragma unroll
    for (int t = 0; t < 4; ++t)
      #pragma unroll
      for (int r = 0; r < 4; ++r) ot[t][r] *= alpha;

    // ---- P^T (C-layout) -> Plds[qm][kn]: 4 packed b64 writes per lane
    #pragma unroll
    for (int t = 0; t < 4; ++t) {
      uint2 pw;
      pw.x = (unsigned int)f2bf(sc[t][0]) | ((unsigned int)f2bf(sc[t][1]) << 16);
      pw.y = (unsigned int)f2bf(sc[t][2]) | ((unsigned int)f2bf(sc[t][3]) << 16);
      *(uint2*)&Plds[wave][l15 * LDK + 16 * t + 4 * quad] = pw;
    }

    // ---- O^T += V^T * P^T  (A=V^T from Vlds, B=P^T from Plds — both b128)
    #pragma unroll
    for (int s = 0; s < 2; ++s) {
      bf16x8 pb = *(const bf16x8*)&Plds[wave][l15 * LDK + 32 * s + quad * 8];
      #pragma unroll
      for (int t = 0; t < 4; ++t) {
        bf16x8 va = *(const bf16x8*)&Vlds[(16 * t + l15) * LDK + 32 * s + quad * 8];
        ot[t] = __builtin_amdgcn_mfma_f32_16x16x32_bf16(va, pb, ot[t], 0, 0, 0);
      }
    }
  }

  // ---- epilogue: O[qm][d] = O^T/l — one float4 store per t
  {
    float inv = 1.0f / lrun;
    float* orow = out + base + (qrow0 + l15) * Ddim + 4 * quad;
    #pragma unroll
    for (int t = 0; t < 4; ++t) {
      f32x4 o4;
      o4.x = ot[t][0] * inv; o4.y = ot[t][1] * inv;
      o4.z = ot[t][2] * inv; o4.w = ot[t][3] * inv;
      *(f32x4*)(orow + 16 * t) = o4;
    }
  }

  // ---- zero-fill attn_weights placeholder, share inverse to compute load:
  // weight w=2g+1 (g=0 heavy-compute -> small fill), prefix over groups = 32*g^2.
  {
    const int w = 2 * g + 1;
    const size_t start_f4 = (size_t)1024 * (32 * (size_t)(g * g) + (size_t)bh * w);
    const size_t count_f4 = (size_t)1024 * w;
    f32x4 z4 = (f32x4){0.f, 0.f, 0.f, 0.f};
    f32x4* zp = (f32x4*)(out + OUT0) + start_f4;
    for (size_t i = tid; i < count_f4; i += 256)
      __builtin_nontemporal_store(z4, zp + i);
  }
}

extern "C" void kernel_launch(void* const* d_in, const int* in_sizes, int n_in,
                              void* d_out, int out_size, void* d_ws, size_t ws_size,
                              hipStream_t stream) {
  const float* q = (const float*)d_in[0];
  const float* k = (const float*)d_in[1];
  const float* v = (const float*)d_in[2];
  float* out = (float*)d_out;
  dim3 grid(BHn * QTiles);   // 1024 blocks: 32 bh * 32 q-tiles, heavy first
  flash_causal_kernel<<<grid, dim3(256), 0, stream>>>(q, k, v, out);
}

// Round 4
// 598.071 us; speedup vs baseline: 1.0694x; 1.0385x over previous
//
#include <hip/hip_runtime.h>

// TurboFlashAttention: causal attention B=2,H=16,S=2048,D=64 fp32, plus 512MB
// zero attn_weights placeholder. R4: double-buffered LDS (1 barrier/iter),
// XOR-swizzled V^T staging (16-way -> 2-way bank conflicts), interleaved
// heavy/light q-tile dispatch for compute/fill overlap.

typedef __bf16 bf16x8 __attribute__((ext_vector_type(8)));
typedef float f32x4 __attribute__((ext_vector_type(4)));

#define LOG2E 1.44269504088896340736f

__device__ __forceinline__ unsigned short f2bf(float f) {
  unsigned int u = __float_as_uint(f);
  u += 0x7fffu + ((u >> 16) & 1u);   // RNE; finite values only
  return (unsigned short)(u >> 16);
}

constexpr int Sdim = 2048, Ddim = 64, BHn = 32;
constexpr int QTiles = 32;
constexpr int LDK = 72;                      // leading-dim pad (shorts)
constexpr int OUT0 = BHn * Sdim * Ddim;      // output-region floats

// V^T swizzle: kn' = kn ^ (8*m), m = ((d>>2) ^ (d>>5)) & 7.
// Keeps 8-short b128 blocks contiguous; spreads b16 write banks to ~2-way.
__device__ __forceinline__ int vswz_m(int d) { return ((d >> 2) ^ (d >> 5)) & 7; }

__global__ __launch_bounds__(256, 3)
void flash_causal_kernel(const float* __restrict__ Q, const float* __restrict__ K,
                         const float* __restrict__ V, float* __restrict__ out) {
  __shared__ unsigned short Klds[2][64 * LDK];   // K tile [kn][d] row-major
  __shared__ unsigned short Vlds[2][64 * LDK];   // V^T tile [d][kn^swz]
  __shared__ unsigned short Plds[4][16 * LDK];   // per-wave P^T round-trip

  const int tid  = threadIdx.x;
  const int wave = tid >> 6;
  const int lane = tid & 63;
  const int quad = lane >> 4;
  const int l15  = lane & 15;

  const int bh = blockIdx.x & (BHn - 1);
  const int g  = (int)(blockIdx.x >> 5);                 // 0..31
  const int qt = (g & 1) ? (QTiles - 1 - (g >> 1)) : (g >> 1);  // 0,31,1,30,...

  const int base  = bh * Sdim * Ddim;
  const int qrow0 = qt * 64 + wave * 16;

  // ---- Q fragment (B-operand: n=l15=qm, k=quad*8+j), 1/sqrt(64) folded.
  bf16x8 aq[2];
  {
    const float* qp = Q + base + (qrow0 + l15) * Ddim + quad * 8;
    #pragma unroll
    for (int s = 0; s < 2; ++s) {
      float4 a = *(const float4*)(qp + 32 * s);
      float4 b = *(const float4*)(qp + 32 * s + 4);
      union { unsigned short u[8]; bf16x8 v; } u;
      u.u[0] = f2bf(a.x * 0.125f); u.u[1] = f2bf(a.y * 0.125f);
      u.u[2] = f2bf(a.z * 0.125f); u.u[3] = f2bf(a.w * 0.125f);
      u.u[4] = f2bf(b.x * 0.125f); u.u[5] = f2bf(b.y * 0.125f);
      u.u[6] = f2bf(b.z * 0.125f); u.u[7] = f2bf(b.w * 0.125f);
      aq[s] = u.v;
    }
  }

  f32x4 ot[4];                                  // O^T rows d=16t+4q+r, col qm=l15
  #pragma unroll
  for (int t = 0; t < 4; ++t) ot[t] = (f32x4){0.f, 0.f, 0.f, 0.f};
  float mrun = -__builtin_inff(), lrun = 0.f;

  const float4* kg4 = (const float4*)(K + base);
  const float4* vg4 = (const float4*)(V + base);

  float4 kf[4], vf[4];

  // regs -> LDS staging (K row-major uint2; V^T swizzled b16 scatter)
  auto stage = [&](int buf) {
    #pragma unroll
    for (int i = 0; i < 4; ++i) {
      int lin = i * 256 + tid;
      int row = lin >> 4;            // kn 0..63
      int c4  = (lin & 15) << 2;     // d 0,4,..,60
      uint2 t2;
      t2.x = (unsigned int)f2bf(kf[i].x) | ((unsigned int)f2bf(kf[i].y) << 16);
      t2.y = (unsigned int)f2bf(kf[i].z) | ((unsigned int)f2bf(kf[i].w) << 16);
      *(uint2*)&Klds[buf][row * LDK + c4] = t2;
      const int sw = vswz_m(c4) << 3;          // same for d=c4..c4+3
      Vlds[buf][(c4 + 0) * LDK + (row ^ sw)] = f2bf(vf[i].x);
      Vlds[buf][(c4 + 1) * LDK + (row ^ sw)] = f2bf(vf[i].y);
      Vlds[buf][(c4 + 2) * LDK + (row ^ sw)] = f2bf(vf[i].z);
      Vlds[buf][(c4 + 3) * LDK + (row ^ sw)] = f2bf(vf[i].w);
    }
  };

  // ---- prologue: tile 0 -> buf 0; prefetch tile 1 into regs
  #pragma unroll
  for (int i = 0; i < 4; ++i) { kf[i] = kg4[i * 256 + tid]; vf[i] = vg4[i * 256 + tid]; }
  stage(0);
  if (qt >= 1) {
    const float4* kp = kg4 + 1024;
    const float4* vp = vg4 + 1024;
    #pragma unroll
    for (int i = 0; i < 4; ++i) { kf[i] = kp[i * 256 + tid]; vf[i] = vp[i * 256 + tid]; }
  }

  for (int j = 0; j <= qt; ++j) {
    __syncthreads();   // buf[j&1] writes visible; buf[(j+1)&1] readers (iter j-1) done
    if (j < qt) stage((j + 1) & 1);
    if (j + 2 <= qt) {
      const float4* kp = kg4 + (j + 2) * 1024;
      const float4* vp = vg4 + (j + 2) * 1024;
      #pragma unroll
      for (int i = 0; i < 4; ++i) { kf[i] = kp[i * 256 + tid]; vf[i] = vp[i * 256 + tid]; }
    }

    const unsigned short* Kb = Klds[j & 1];
    const unsigned short* Vb = Vlds[j & 1];

    // ---- S^T = K * Q^T  (C-layout: S^T[kn=16t+4q+r][qm=l15])
    f32x4 sc[4];
    #pragma unroll
    for (int t = 0; t < 4; ++t) sc[t] = (f32x4){0.f, 0.f, 0.f, 0.f};
    #pragma unroll
    for (int s = 0; s < 2; ++s) {
      #pragma unroll
      for (int t = 0; t < 4; ++t) {
        bf16x8 ka = *(const bf16x8*)&Kb[(16 * t + l15) * LDK + 32 * s + quad * 8];
        sc[t] = __builtin_amdgcn_mfma_f32_16x16x32_bf16(ka, aq[s], sc[t], 0, 0, 0);
      }
    }

    // ---- causal mask (diagonal tile)
    if (j == qt) {
      const int qml = wave * 16 + l15;
      #pragma unroll
      for (int t = 0; t < 4; ++t)
        #pragma unroll
        for (int r = 0; r < 4; ++r)
          if (16 * t + 4 * quad + r > qml) sc[t][r] = -__builtin_inff();
    }

    // ---- online softmax: per-lane row + 2 cross-quad shuffles
    float mx = sc[0][0];
    #pragma unroll
    for (int t = 0; t < 4; ++t)
      #pragma unroll
      for (int r = 0; r < 4; ++r) mx = fmaxf(mx, sc[t][r]);
    mx = fmaxf(mx, __shfl_xor(mx, 16));
    mx = fmaxf(mx, __shfl_xor(mx, 32));
    float mn    = fmaxf(mrun, mx);
    float alpha = __builtin_amdgcn_exp2f((mrun - mn) * LOG2E);
    float msc   = mn * LOG2E;
    mrun = mn;
    float rs = 0.f;
    #pragma unroll
    for (int t = 0; t < 4; ++t)
      #pragma unroll
      for (int r = 0; r < 4; ++r) {
        float p = __builtin_amdgcn_exp2f(fmaf(sc[t][r], LOG2E, -msc));
        sc[t][r] = p;
        rs += p;
      }
    rs += __shfl_xor(rs, 16);
    rs += __shfl_xor(rs, 32);
    lrun = lrun * alpha + rs;
    #pragma unroll
    for (int t = 0; t < 4; ++t)
      #pragma unroll
      for (int r = 0; r < 4; ++r) ot[t][r] *= alpha;

    // ---- P^T -> Plds (packed b64), then b128 B-frags
    #pragma unroll
    for (int t = 0; t < 4; ++t) {
      uint2 pw;
      pw.x = (unsigned int)f2bf(sc[t][0]) | ((unsigned int)f2bf(sc[t][1]) << 16);
      pw.y = (unsigned int)f2bf(sc[t][2]) | ((unsigned int)f2bf(sc[t][3]) << 16);
      *(uint2*)&Plds[wave][l15 * LDK + 16 * t + 4 * quad] = pw;
    }

    // ---- O^T += V^T * P^T
    #pragma unroll
    for (int s = 0; s < 2; ++s) {
      bf16x8 pb = *(const bf16x8*)&Plds[wave][l15 * LDK + 32 * s + quad * 8];
      #pragma unroll
      for (int t = 0; t < 4; ++t) {
        const int d = 16 * t + l15;
        const int knb = ((4 * s + quad) ^ vswz_m(d)) << 3;
        bf16x8 va = *(const bf16x8*)&Vb[d * LDK + knb];
        ot[t] = __builtin_amdgcn_mfma_f32_16x16x32_bf16(va, pb, ot[t], 0, 0, 0);
      }
    }
  }

  // ---- epilogue: O[qm][d] = O^T / l
  {
    float inv = 1.0f / lrun;
    float* orow = out + base + (qrow0 + l15) * Ddim + 4 * quad;
    #pragma unroll
    for (int t = 0; t < 4; ++t) {
      f32x4 o4;
      o4.x = ot[t][0] * inv; o4.y = ot[t][1] * inv;
      o4.z = ot[t][2] * inv; o4.w = ot[t][3] * inv;
      *(f32x4*)(orow + 16 * t) = o4;
    }
  }

  // ---- zero-fill attn_weights, share inverse to compute load (fill-rank g').
  {
    const int gp = (QTiles - 1) - qt;            // 0 (heavy compute) .. 31
    const int w  = 2 * gp + 1;
    const size_t start_f4 = (size_t)1024 * (32 * (size_t)(gp * gp) + (size_t)bh * w);
    const size_t count_f4 = (size_t)1024 * w;
    f32x4 z4 = (f32x4){0.f, 0.f, 0.f, 0.f};
    f32x4* zp = (f32x4*)(out + OUT0) + start_f4;
    for (size_t i = tid; i < count_f4; i += 256)
      __builtin_nontemporal_store(z4, zp + i);
  }
}

extern "C" void kernel_launch(void* const* d_in, const int* in_sizes, int n_in,
                              void* d_out, int out_size, void* d_ws, size_t ws_size,
                              hipStream_t stream) {
  const float* q = (const float*)d_in[0];
  const float* k = (const float*)d_in[1];
  const float* v = (const float*)d_in[2];
  float* out = (float*)d_out;
  dim3 grid(BHn * QTiles);   // 1024 blocks: 32 bh x 32 q-tiles, interleaved
  flash_causal_kernel<<<grid, dim3(256), 0, stream>>>(q, k, v, out);
}

// Round 5
// 586.570 us; speedup vs baseline: 1.0904x; 1.0196x over previous
//
#include <hip/hip_runtime.h>

// TurboFlashAttention: causal B=2,H=16,S=2048,D=64 fp32 + 512MB zero placeholder.
// R5: 2 q-tiles per block (128 rows) — halves K/V re-read traffic (540->272MB),
// halves LDS staging + barriers; shared K/V fragment reads serve both q-frags.
// Double-buffered LDS, swizzled V^T staging, inverse-balanced zero-fill.

typedef __bf16 bf16x8 __attribute__((ext_vector_type(8)));
typedef float f32x4 __attribute__((ext_vector_type(4)));

#define LOG2E 1.44269504088896340736f

__device__ __forceinline__ unsigned short f2bf(float f) {
  unsigned int u = __float_as_uint(f);
  u += 0x7fffu + ((u >> 16) & 1u);   // RNE
  return (unsigned short)(u >> 16);
}

constexpr int Sdim = 2048, Ddim = 64, BHn = 32;
constexpr int STiles = 16;                   // 128-row q-supertiles
constexpr int LDK = 72;                      // LDS leading-dim pad (shorts)
constexpr int OUT0 = BHn * Sdim * Ddim;      // output-region floats
constexpr size_t FILL_PER_BH = 1048576;      // f32x4 per bh in placeholder

__device__ __forceinline__ int vswz_m(int d) { return ((d >> 2) ^ (d >> 5)) & 7; }

__global__ __launch_bounds__(256, 2)
void flash_causal_kernel(const float* __restrict__ Q, const float* __restrict__ K,
                         const float* __restrict__ V, float* __restrict__ out) {
  __shared__ unsigned short Klds[2][64 * LDK];      // K tile [kn][d]
  __shared__ unsigned short Vlds[2][64 * LDK];      // V^T tile [d][kn^swz]
  __shared__ unsigned short Plds[4][2][16 * LDK];   // per-wave, per-frag P^T

  const int tid  = threadIdx.x;
  const int wave = tid >> 6;
  const int lane = tid & 63;
  const int quad = lane >> 4;
  const int l15  = lane & 15;

  const int bh = blockIdx.x & (BHn - 1);
  const int g  = (int)(blockIdx.x >> 5);                        // 0..15
  const int s  = (g & 1) ? (STiles - 1) - (g >> 1) : (g >> 1);  // interleave
  const int jmax = 2 * s + 1;

  const int base  = bh * Sdim * Ddim;
  const int qbase = s * 128;

  // ---- Q fragments (B-operand), scale 1/8 folded. frag f: rows qbase+64f+16w.
  bf16x8 aq[2][2];
  #pragma unroll
  for (int f = 0; f < 2; ++f) {
    const float* qp = Q + base + (qbase + 64 * f + wave * 16 + l15) * Ddim + quad * 8;
    #pragma unroll
    for (int s2 = 0; s2 < 2; ++s2) {
      float4 a = *(const float4*)(qp + 32 * s2);
      float4 b = *(const float4*)(qp + 32 * s2 + 4);
      union { unsigned short u[8]; bf16x8 v; } u;
      u.u[0] = f2bf(a.x * 0.125f); u.u[1] = f2bf(a.y * 0.125f);
      u.u[2] = f2bf(a.z * 0.125f); u.u[3] = f2bf(a.w * 0.125f);
      u.u[4] = f2bf(b.x * 0.125f); u.u[5] = f2bf(b.y * 0.125f);
      u.u[6] = f2bf(b.z * 0.125f); u.u[7] = f2bf(b.w * 0.125f);
      aq[f][s2] = u.v;
    }
  }

  f32x4 ot[2][4];
  #pragma unroll
  for (int f = 0; f < 2; ++f)
    #pragma unroll
    for (int t = 0; t < 4; ++t) ot[f][t] = (f32x4){0.f, 0.f, 0.f, 0.f};
  float mrun[2] = {-__builtin_inff(), -__builtin_inff()};
  float lrun[2] = {0.f, 0.f};

  const float4* kg4 = (const float4*)(K + base);
  const float4* vg4 = (const float4*)(V + base);
  float4 kf[4], vf[4];

  auto ldtile = [&](int j) {
    const float4* kp = kg4 + j * 1024;
    const float4* vp = vg4 + j * 1024;
    #pragma unroll
    for (int i = 0; i < 4; ++i) { kf[i] = kp[i * 256 + tid]; vf[i] = vp[i * 256 + tid]; }
  };
  auto stage = [&](int buf) {
    #pragma unroll
    for (int i = 0; i < 4; ++i) {
      int lin = i * 256 + tid;
      int row = lin >> 4;
      int c4  = (lin & 15) << 2;
      uint2 t2;
      t2.x = (unsigned int)f2bf(kf[i].x) | ((unsigned int)f2bf(kf[i].y) << 16);
      t2.y = (unsigned int)f2bf(kf[i].z) | ((unsigned int)f2bf(kf[i].w) << 16);
      *(uint2*)&Klds[buf][row * LDK + c4] = t2;
      const int sw = vswz_m(c4) << 3;
      Vlds[buf][(c4 + 0) * LDK + (row ^ sw)] = f2bf(vf[i].x);
      Vlds[buf][(c4 + 1) * LDK + (row ^ sw)] = f2bf(vf[i].y);
      Vlds[buf][(c4 + 2) * LDK + (row ^ sw)] = f2bf(vf[i].z);
      Vlds[buf][(c4 + 3) * LDK + (row ^ sw)] = f2bf(vf[i].w);
    }
  };

  // ---- prologue
  ldtile(0); stage(0); ldtile(1);   // jmax >= 1 always

  for (int j = 0; j <= jmax; ++j) {
    __syncthreads();
    if (j < jmax) stage((j + 1) & 1);
    if (j + 2 <= jmax) ldtile(j + 2);

    const unsigned short* Kb = Klds[j & 1];
    const unsigned short* Vb = Vlds[j & 1];
    const bool f0act = (j <= 2 * s);   // frag0 has no columns at j == jmax

    // ---- S^T for both frags; K fragment read once, used twice
    f32x4 sc[2][4];
    #pragma unroll
    for (int f = 0; f < 2; ++f)
      #pragma unroll
      for (int t = 0; t < 4; ++t) sc[f][t] = (f32x4){0.f, 0.f, 0.f, 0.f};
    #pragma unroll
    for (int s2 = 0; s2 < 2; ++s2) {
      #pragma unroll
      for (int t = 0; t < 4; ++t) {
        bf16x8 ka = *(const bf16x8*)&Kb[(16 * t + l15) * LDK + 32 * s2 + quad * 8];
        sc[0][t] = __builtin_amdgcn_mfma_f32_16x16x32_bf16(ka, aq[0][s2], sc[0][t], 0, 0, 0);
        sc[1][t] = __builtin_amdgcn_mfma_f32_16x16x32_bf16(ka, aq[1][s2], sc[1][t], 0, 0, 0);
      }
    }

    // ---- causal diagonal masks (frag f diag at j == 2s+f; local coords equal)
    #pragma unroll
    for (int f = 0; f < 2; ++f) {
      if (j == 2 * s + f) {
        const int qml = wave * 16 + l15;
        #pragma unroll
        for (int t = 0; t < 4; ++t)
          #pragma unroll
          for (int r = 0; r < 4; ++r)
            if (16 * t + 4 * quad + r > qml) sc[f][t][r] = -__builtin_inff();
      }
    }

    // ---- online softmax + P write (per frag; frag0 skipped on final odd iter)
    #pragma unroll
    for (int f = 0; f < 2; ++f) {
      if (f == 0 && !f0act) continue;
      float mx = sc[f][0][0];
      #pragma unroll
      for (int t = 0; t < 4; ++t)
        #pragma unroll
        for (int r = 0; r < 4; ++r) mx = fmaxf(mx, sc[f][t][r]);
      mx = fmaxf(mx, __shfl_xor(mx, 16));
      mx = fmaxf(mx, __shfl_xor(mx, 32));
      float mn    = fmaxf(mrun[f], mx);
      float alpha = __builtin_amdgcn_exp2f((mrun[f] - mn) * LOG2E);
      float msc   = mn * LOG2E;
      mrun[f] = mn;
      float rs = 0.f;
      #pragma unroll
      for (int t = 0; t < 4; ++t)
        #pragma unroll
        for (int r = 0; r < 4; ++r) {
          float p = __builtin_amdgcn_exp2f(fmaf(sc[f][t][r], LOG2E, -msc));
          sc[f][t][r] = p;
          rs += p;
        }
      rs += __shfl_xor(rs, 16);
      rs += __shfl_xor(rs, 32);
      lrun[f] = lrun[f] * alpha + rs;
      #pragma unroll
      for (int t = 0; t < 4; ++t)
        #pragma unroll
        for (int r = 0; r < 4; ++r) ot[f][t][r] *= alpha;
      #pragma unroll
      for (int t = 0; t < 4; ++t) {
        uint2 pw;
        pw.x = (unsigned int)f2bf(sc[f][t][0]) | ((unsigned int)f2bf(sc[f][t][1]) << 16);
        pw.y = (unsigned int)f2bf(sc[f][t][2]) | ((unsigned int)f2bf(sc[f][t][3]) << 16);
        *(uint2*)&Plds[wave][f][l15 * LDK + 16 * t + 4 * quad] = pw;
      }
    }

    // ---- O^T += V^T * P^T; V fragment read once, used for both frags
    #pragma unroll
    for (int s2 = 0; s2 < 2; ++s2) {
      bf16x8 pb0, pb1;
      if (f0act) pb0 = *(const bf16x8*)&Plds[wave][0][l15 * LDK + 32 * s2 + quad * 8];
      pb1 = *(const bf16x8*)&Plds[wave][1][l15 * LDK + 32 * s2 + quad * 8];
      #pragma unroll
      for (int t = 0; t < 4; ++t) {
        const int d = 16 * t + l15;
        bf16x8 va = *(const bf16x8*)&Vb[d * LDK + (((4 * s2 + quad) ^ vswz_m(d)) << 3)];
        if (f0act)
          ot[0][t] = __builtin_amdgcn_mfma_f32_16x16x32_bf16(va, pb0, ot[0][t], 0, 0, 0);
        ot[1][t] = __builtin_amdgcn_mfma_f32_16x16x32_bf16(va, pb1, ot[1][t], 0, 0, 0);
      }
    }
  }

  // ---- epilogue
  #pragma unroll
  for (int f = 0; f < 2; ++f) {
    float inv = 1.0f / lrun[f];
    float* orow = out + base + (qbase + 64 * f + wave * 16 + l15) * Ddim + 4 * quad;
    #pragma unroll
    for (int t = 0; t < 4; ++t) {
      f32x4 o4;
      o4.x = ot[f][t][0] * inv; o4.y = ot[f][t][1] * inv;
      o4.z = ot[f][t][2] * inv; o4.w = ot[f][t][3] * inv;
      *(f32x4*)(orow + 16 * t) = o4;
    }
  }

  // ---- zero-fill placeholder, share inverse to compute (fill-rank gp).
  {
    const int gp = (STiles - 1) - s;             // 0 = heaviest compute
    const int w  = 2 * gp + 1;
    const size_t start_f4 = (size_t)bh * FILL_PER_BH + (size_t)4096 * (gp * gp);
    const size_t count_f4 = (size_t)4096 * w;
    f32x4 z4 = (f32x4){0.f, 0.f, 0.f, 0.f};
    f32x4* zp = (f32x4*)(out + OUT0) + start_f4;
    for (size_t i = tid; i < count_f4; i += 256)
      __builtin_nontemporal_store(z4, zp + i);
  }
}

extern "C" void kernel_launch(void* const* d_in, const int* in_sizes, int n_in,
                              void* d_out, int out_size, void* d_ws, size_t ws_size,
                              hipStream_t stream) {
  const float* q = (const float*)d_in[0];
  const float* k = (const float*)d_in[1];
  const float* v = (const float*)d_in[2];
  float* out = (float*)d_out;
  dim3 grid(BHn * STiles);   // 512 blocks: 32 bh x 16 supertiles, all co-resident
  flash_causal_kernel<<<grid, dim3(256), 0, stream>>>(q, k, v, out);
}